// Round 5
// baseline (310.434 us; speedup 1.0000x reference)
//
#include <hip/hip_runtime.h>
#include <math.h>

#define B_    32
#define A_    8400
#define M_    40
#define NC_   80
#define TOPK_ 10
#define EPS_  1e-9f

#define NTHR  524288   // k_init_dfl grid is EXACTLY 2048 x 256 = NTHR threads

// ---------------------------------------------------------------- CIoU
__device__ __forceinline__ float ciou_f(float b1x1, float b1y1, float b1x2, float b1y2,
                                        float b2x1, float b2y1, float b2x2, float b2y2) {
    const float eps = 1e-7f;
    float w1 = b1x2 - b1x1, h1 = b1y2 - b1y1 + eps;
    float w2 = b2x2 - b2x1, h2 = b2y2 - b2y1 + eps;
    float iw = fminf(b1x2, b2x2) - fmaxf(b1x1, b2x1);
    float ih = fminf(b1y2, b2y2) - fmaxf(b1y1, b2y1);
    float inter = fmaxf(iw, 0.f) * fmaxf(ih, 0.f);
    float uni = w1 * h1 + w2 * h2 - inter + eps;
    float iou = inter / uni;
    float cw = fmaxf(b1x2, b2x2) - fminf(b1x1, b2x1);
    float ch = fmaxf(b1y2, b2y2) - fminf(b1y1, b2y1);
    float c2 = cw * cw + ch * ch + eps;
    float dx = b2x1 + b2x2 - b1x1 - b1x2;
    float dy = b2y1 + b2y2 - b1y1 - b1y2;
    float rho2 = (dx * dx + dy * dy) * 0.25f;
    float da = atanf(w2 / h2) - atanf(w1 / h1);
    float v = 0.4052847345693511f * da * da;       // 4/pi^2
    float alpha = v / (v - iou + 1.f + eps);
    return iou - (rho2 / c2 + v * alpha);
}

// closed-form anchor: grid-unit center (ax,ay) and stride s for anchor index a
__device__ __forceinline__ void anchor_of(int a, float& ax, float& ay, float& s) {
    if (a < 6400)      { s = 8.f;  int r = a;        ax = (float)(r % 80) + 0.5f; ay = (float)(r / 80) + 0.5f; }
    else if (a < 8000) { s = 16.f; int r = a - 6400; ax = (float)(r % 40) + 0.5f; ay = (float)(r / 40) + 0.5f; }
    else               { s = 32.f; int r = a - 8000; ax = (float)(r % 20) + 0.5f; ay = (float)(r / 20) + 0.5f; }
}

// masked overlap at (b, gt-box g, anchor a); 0 if anchor center outside box
__device__ __forceinline__ float ov_at2(const float* __restrict__ pb,
                                        float g0, float g1, float g2, float g3,
                                        int b, int a) {
    float ax, ay, s; anchor_of(a, ax, ay, s);
    float axp = ax * s, ayp = ay * s;
    if (!((axp - g0) > EPS_ && (ayp - g1) > EPS_ && (g2 - axp) > EPS_ && (g3 - ayp) > EPS_))
        return 0.f;
    const float4 p = *(const float4*)(pb + ((size_t)b * A_ + a) * 4);
    float c = ciou_f(g0, g1, g2, g3, p.x * s, p.y * s, p.z * s, p.w * s);
    return fmaxf(c, 0.f);
}

__device__ __forceinline__ unsigned long long shflxor_u64(unsigned long long v, int m) {
    int lo = __shfl_xor((int)(unsigned)(v & 0xffffffffull), m, 64);
    int hi = __shfl_xor((int)(unsigned)(v >> 32), m, 64);
    return ((unsigned long long)(unsigned)hi << 32) | (unsigned)lo;
}

// ---- DPP cross-lane helpers (VALU pipe, no LDS) --------------------------
// quad xor-add: v += xor1(v); v += xor2(v)
__device__ __forceinline__ float qsum_dpp(float v) {
    int y = __builtin_amdgcn_update_dpp(0, __float_as_int(v), 0xB1, 0xF, 0xF, true);   // quad_perm xor1
    float r = v + __int_as_float(y);
    int z = __builtin_amdgcn_update_dpp(0, __float_as_int(r), 0x4E, 0xF, 0xF, true);   // quad_perm xor2
    return r + __int_as_float(z);
}

template <int CTRL>
__device__ __forceinline__ unsigned long long dpp64(unsigned long long v) {
    unsigned lo = (unsigned)__builtin_amdgcn_update_dpp(0, (int)(unsigned)v, CTRL, 0xF, 0xF, true);
    unsigned hi = (unsigned)__builtin_amdgcn_update_dpp(0, (int)(unsigned)(v >> 32), CTRL, 0xF, 0xF, true);
    return ((unsigned long long)hi << 32) | lo;
}

__device__ __forceinline__ unsigned long long max64(unsigned long long a, unsigned long long b) {
    return a > b ? a : b;
}

__device__ __forceinline__ unsigned long long swz16_64(unsigned long long v) {
    unsigned lo = (unsigned)__builtin_amdgcn_ds_swizzle((int)(unsigned)v, 0x401F);        // xor16 (BitMode)
    unsigned hi = (unsigned)__builtin_amdgcn_ds_swizzle((int)(unsigned)(v >> 32), 0x401F);
    return ((unsigned long long)hi << 32) | lo;
}

// all-lanes max of u64 key across the wave (valid under max-reduce block-uniformity)
__device__ __forceinline__ unsigned long long wave_max_u64(unsigned long long w) {
    w = max64(w, dpp64<0xB1>(w));    // xor1
    w = max64(w, dpp64<0x4E>(w));    // xor2
    w = max64(w, dpp64<0x141>(w));   // row_half_mirror (covers 8-group)
    w = max64(w, dpp64<0x140>(w));   // row_mirror      (covers 16-group)
    w = max64(w, swz16_64(w));       // xor16           (covers 32-group)
    w = max64(w, shflxor_u64(w, 32));// xor32           (covers 64)
    return w;
}

// quad-cooperative 16-bin softmax-expectation; f is the float4 index
__device__ __forceinline__ void dfl_quad(float4 v, int f, float* __restrict__ pb) {
    int q = f & 3;
    float e0 = __expf(v.x), e1 = __expf(v.y), e2 = __expf(v.z), e3 = __expf(v.w);
    float se = e0 + e1 + e2 + e3;
    float sd = e1 + 2.f * e2 + 3.f * e3 + (float)(4 * q) * se;
    se = qsum_dpp(se);
    sd = qsum_dpp(sd);
    float dist = sd / se;
    // lane i reads lane i+N ==> row_shl:N (0x100+N)
    int di = __float_as_int(dist);
    float d1 = __int_as_float(__builtin_amdgcn_update_dpp(0, di, 0x104, 0xF, 0xF, true)); // row_shl:4
    float d2 = __int_as_float(__builtin_amdgcn_update_dpp(0, di, 0x108, 0xF, 0xF, true)); // row_shl:8
    float d3 = __int_as_float(__builtin_amdgcn_update_dpp(0, di, 0x10C, 0xF, 0xF, true)); // row_shl:12
    if ((f & 15) == 0) {
        int aidx = f >> 4;
        int a = aidx % A_;
        float ax, ay, s; anchor_of(a, ax, ay, s);
        ((float4*)pb)[aidx] = make_float4(ax - dist, ay - d1, ax + d2, ay + d3);
    }
}

__device__ __forceinline__ float bce4(float4 x) {
    return fmaxf(x.x, 0.f) + __logf(1.f + __expf(-fabsf(x.x)))
         + fmaxf(x.y, 0.f) + __logf(1.f + __expf(-fabsf(x.y)))
         + fmaxf(x.z, 0.f) + __logf(1.f + __expf(-fabsf(x.z)))
         + fmaxf(x.w, 0.f) + __logf(1.f + __expf(-fabsf(x.w)));
}

// ------------------------------------------- K1: init + DFL-decode only
// Grid MUST be 2048 x 256 (= NTHR threads); NF4 = 4,300,800 = 8*NTHR + 106,496
// __launch_bounds__(256,4): 4 blocks/CU target -> VGPR budget 128, lets the
// 8 float4 loads actually stay in flight (round-2/4 counters showed VGPR=32
// i.e. the allocator was serializing the batch).
__global__ __launch_bounds__(256, 4) void k_init_dfl(
        const float4* __restrict__ d4,
        float* __restrict__ pb,
        unsigned long long* __restrict__ abits64,
        unsigned long long* __restrict__ ovmax) {
    const int tid0 = blockIdx.x * blockDim.x + threadIdx.x;
    if (tid0 < B_ * A_) {
        abits64[tid0] = 0ull;
        ovmax[tid0] = 0x00000000FFFFFFFFull;       // (ov=0.0, m=0)
    }
    const int NF4 = B_ * A_ * 16;
    float4 v0 = d4[tid0];
    float4 v1 = d4[tid0 + NTHR];
    float4 v2 = d4[tid0 + 2 * NTHR];
    float4 v3 = d4[tid0 + 3 * NTHR];
    float4 v4 = d4[tid0 + 4 * NTHR];
    float4 v5 = d4[tid0 + 5 * NTHR];
    float4 v6 = d4[tid0 + 6 * NTHR];
    float4 v7 = d4[tid0 + 7 * NTHR];
    dfl_quad(v0, tid0, pb);
    dfl_quad(v1, tid0 + NTHR, pb);
    dfl_quad(v2, tid0 + 2 * NTHR, pb);
    dfl_quad(v3, tid0 + 3 * NTHR, pb);
    dfl_quad(v4, tid0 + 4 * NTHR, pb);
    dfl_quad(v5, tid0 + 5 * NTHR, pb);
    dfl_quad(v6, tid0 + 6 * NTHR, pb);
    dfl_quad(v7, tid0 + 7 * NTHR, pb);
    int f8 = tid0 + 8 * NTHR;
    if (f8 < NF4) dfl_quad(d4[f8], f8, pb);        // wave-uniform tail
}

// ------------------------------------------- K2: rect-scan align + top-10, 4 waves/block
__global__ __launch_bounds__(256) void k_aligntopk(
    const float* __restrict__ scores, const float* __restrict__ pb,
    const float* __restrict__ gt, const float* __restrict__ mgt,
    const int* __restrict__ glab, unsigned int* __restrict__ abits,
    unsigned long long* __restrict__ ovmax) {
    __shared__ unsigned long long sh[4 * TOPK_];
    int bm = blockIdx.x;
    if (mgt[bm] <= 0.f) return;                 // uniform early-exit, no barrier reached
    int b = bm / M_, m = bm % M_;
    int lab = glab[bm];
    const float g0 = gt[bm * 4 + 0], g1 = gt[bm * 4 + 1];
    const float g2 = gt[bm * 4 + 2], g3 = gt[bm * 4 + 3];
    int tid  = threadIdx.x;
    int lane = tid & 63;
    int wv   = tid >> 6;

    const int   Wl[3]  = { 80, 40, 20 };
    const int   Bs[3]  = { 0, 6400, 8000 };
    const float Sl[3]  = { 8.f, 16.f, 32.f };
    int jlo[3], ilo[3], rw[3], cnt[3];
#pragma unroll
    for (int l = 0; l < 3; l++) {
        float s = Sl[l]; int W = Wl[l];
        int jl = max(0, (int)floorf(g0 / s - 0.5f) - 1);
        int jh = min(W - 1, (int)ceilf(g2 / s - 0.5f) + 1);
        int il = max(0, (int)floorf(g1 / s - 0.5f) - 1);
        int ih = min(W - 1, (int)ceilf(g3 / s - 0.5f) + 1);
        int w = jh - jl + 1, h = ih - il + 1;
        jlo[l] = jl; ilo[l] = il; rw[l] = max(w, 0);
        cnt[l] = (w > 0 && h > 0) ? w * h : 0;
    }
    int c01 = cnt[0] + cnt[1];
    int tot = c01 + cnt[2];

    unsigned long long t[TOPK_];
#pragma unroll
    for (int k = 0; k < TOPK_; k++) t[k] = 0ull;

    for (int c = tid; c < tot; c += 256) {
        int l = (c < cnt[0]) ? 0 : ((c < c01) ? 1 : 2);
        int r = c - ((l == 0) ? 0 : ((l == 1) ? cnt[0] : c01));
        int w = rw[l];
        int di = r / w, dj = r - di * w;
        int i = ilo[l] + di, j = jlo[l] + dj;
        float s = Sl[l];
        float ax = ((float)j + 0.5f) * s;
        float ay = ((float)i + 0.5f) * s;
        if (!((ax - g0) > EPS_ && (ay - g1) > EPS_ && (g2 - ax) > EPS_ && (g3 - ay) > EPS_))
            continue;
        int a = Bs[l] + i * Wl[l] + j;
        // issue BOTH gathers before CIoU so the two latencies overlap
        const float4 p = *(const float4*)(pb + ((size_t)b * A_ + a) * 4);
        float sc = scores[((size_t)b * A_ + a) * NC_ + lab];
        float ci = ciou_f(g0, g1, g2, g3, p.x * s, p.y * s, p.z * s, p.w * s);
        float ov = fmaxf(ci, 0.f);
        float al = 0.f;
        if (ov > 0.f) {
            unsigned long long opk = ((unsigned long long)__float_as_uint(ov) << 32)
                                     | (unsigned)(~(unsigned)m);
            atomicMax(&ovmax[(size_t)b * A_ + a], opk);
            float bs = 1.f / (1.f + __expf(-sc));
            float o2 = ov * ov;
            al = sqrtf(bs) * o2 * o2 * o2;     // bs^0.5 * ov^6
        }
        unsigned long long pkd = ((unsigned long long)__float_as_uint(al) << 32)
                                 | (unsigned)(~(unsigned)a);
        if (pkd > t[TOPK_ - 1]) {
            unsigned long long cv = pkd;
#pragma unroll
            for (int k = 0; k < TOPK_; k++) {
                bool g = cv > t[k];
                unsigned long long o = t[k];
                t[k] = g ? cv : o;
                cv   = g ? o : cv;
            }
        }
    }

    // per-wave top-10 extraction: after this, lanes 0..9 hold the wave's top-10
    unsigned long long mysel = 0ull;
#pragma unroll
    for (int k = 0; k < TOPK_; k++) {
        unsigned long long w = wave_max_u64(t[0]);
        if (lane == k) mysel = w;
        if (w != 0ull && t[0] == w) {
#pragma unroll
            for (int q = 0; q < TOPK_ - 1; q++) t[q] = t[q + 1];
            t[TOPK_ - 1] = 0ull;
        }
    }
    if (lane < TOPK_) sh[wv * TOPK_ + lane] = mysel;
    __syncthreads();
    if (wv != 0) return;                        // no barriers after this point

    // wave 0: merge 40 candidates (keys unique -> exact global top-10)
    unsigned long long val = (lane < 4 * TOPK_) ? sh[lane] : 0ull;
    unsigned long long fin = 0ull;
#pragma unroll
    for (int k = 0; k < TOPK_; k++) {
        unsigned long long w = wave_max_u64(val);
        if (lane == k) fin = w;
        if (w != 0ull && val == w) val = 0ull;
    }

    float sval = __uint_as_float((unsigned)(fin >> 32));
    int   sidx = (int)(~(unsigned)fin);
    unsigned int bit = 1u << (m & 31);
    int word = (m >= 32) ? 1 : 0;
    bool keep = (lane < TOPK_) && (sval > EPS_);
    if (keep) atomicOr(&abits[2 * ((size_t)b * A_ + sidx) + word], bit);
    unsigned long long kb = __ballot(keep);
    if (lane == 0 && __popcll(kb) < TOPK_) {
        float ax = 4.f, ay = 4.f;               // anchor 0 center in pixels
        if ((ax - g0) > EPS_ && (ay - g1) > EPS_ && (g2 - ax) > EPS_ && (g3 - ay) > EPS_)
            atomicOr(&abits[2 * ((size_t)b * A_) + word], bit);
    }
}

// ------------------------------------------- K3: resolve + per-anchor (ov,al) + per-gt maxima
__global__ __launch_bounds__(256) void k_R(
    const unsigned int* __restrict__ abits,
    const unsigned long long* __restrict__ ovmax,
    const float* __restrict__ pb,
    const float* __restrict__ scores, const float* __restrict__ gt,
    const int* __restrict__ glab,
    int* __restrict__ tgti, float* __restrict__ alv,
    int* __restrict__ pa_g, int* __restrict__ po_g) {
    int idx = blockIdx.x * blockDim.x + threadIdx.x;
    if (idx >= B_ * A_) return;
    unsigned int lo = abits[2 * idx], hi = abits[2 * idx + 1];
    int fg = __popc(lo) + __popc(hi);
    if (fg == 0) { tgti[idx] = -1; return; }
    int b = idx / A_, a = idx % A_;
    int tgt; float ov;
    if (fg > 1) {
        unsigned long long pk = ovmax[idx];    // precomputed argmax over masked overlaps
        tgt = (int)(~(unsigned)(pk & 0xffffffffull));
        ov  = __uint_as_float((unsigned)(pk >> 32));
    } else {
        tgt = lo ? (__ffs(lo) - 1) : (32 + __ffs(hi) - 1);
        int bmi = b * M_ + tgt;
        ov = ov_at2(pb, gt[bmi * 4], gt[bmi * 4 + 1], gt[bmi * 4 + 2], gt[bmi * 4 + 3], b, a);
    }
    float al = 0.f;
    if (ov > 0.f) {
        int lab = glab[b * M_ + tgt];
        float sc = scores[(size_t)idx * NC_ + lab];
        float bs = 1.f / (1.f + __expf(-sc));
        float o2 = ov * ov;
        al = sqrtf(bs) * o2 * o2 * o2;
    }
    tgti[idx] = tgt;
    alv[idx] = al;
    int bmi = b * M_ + tgt;
    atomicMax(&pa_g[bmi], __float_as_int(al));   // fire-and-forget
    atomicMax(&po_g[bmi], __float_as_int(ov));
}

// ------------------------------------------- K4: BCE half-row + norm + tss + CIoU + DFL
// 2 threads per anchor (g = anchor*2 + half). Grid 2100 x 256 = 537,600 = 2*B*A exactly.
// half h: BCE over classes [h*40, h*40+40) via reg-array (10 float4 in flight),
//         DFL sides {2h, 2h+1}; CIoU/ts/label-term on h==0 only.
__global__ __launch_bounds__(256, 4) void k_S(
    const int* __restrict__ tgti, const float* __restrict__ alv,
    const int* __restrict__ pa_g, const int* __restrict__ po_g,
    const float* __restrict__ scores, const float* __restrict__ pb,
    const float* __restrict__ gt, const int* __restrict__ glab,
    const float* __restrict__ distri, float* __restrict__ acc) {
    int g = blockIdx.x * blockDim.x + threadIdx.x;   // 0 .. 2*B*A-1
    int idx  = g >> 1;
    int half = g & 1;
    float ts = 0.f, cs = 0.f, liou = 0.f, ldfl = 0.f;
    {
        // target-free BCE over this thread's half class row (contiguous 160B)
        const float4* srow = (const float4*)(scores + (size_t)idx * NC_ + half * (NC_ / 2));
        float4 r[10];
#pragma unroll
        for (int i = 0; i < 10; i++) r[i] = srow[i];
        float bsum = 0.f;
#pragma unroll
        for (int i = 0; i < 10; i++) bsum += bce4(r[i]);
        cs = bsum;
        int tgt = tgti[idx];
        if (tgt >= 0) {
            int b = idx / A_, a = idx % A_;
            int bmi = b * M_ + tgt;
            float al = alv[idx];
            float pa = __int_as_float(pa_g[bmi]);
            float po = __int_as_float(po_g[bmi]);
            float nv = al * po / (pa + EPS_);
            float ax, ay, s; anchor_of(a, ax, ay, s);
            const float* gb = gt + (size_t)bmi * 4;
            float t0 = gb[0] / s, t1 = gb[1] / s, t2 = gb[2] / s, t3 = gb[3] / s;
            if (half == 0) {
                ts = nv;
                int lab = max(glab[bmi], 0);
                float sc = scores[(size_t)idx * NC_ + lab];
                cs -= sc * nv;
                const float4 p = *(const float4*)(pb + (size_t)idx * 4);
                float iou = ciou_f(p.x, p.y, p.z, p.w, t0, t1, t2, t3);
                liou = (1.f - iou) * nv;
            }
            // DFL: this half's two sides (contiguous 128B of distri)
            float tg4[4] = { ax - t0, ay - t1, t2 - ax, t3 - ay };
            const float* dd = distri + (size_t)idx * 64 + half * 32;
            float dfl = 0.f;
#pragma unroll
            for (int sdi = 0; sdi < 2; sdi++) {
                int sd = 2 * half + sdi;
                float tvv = fminf(fmaxf(tg4[sd], 0.f), 14.99f);
                int tl = (int)tvv;
                float wl = (float)(tl + 1) - tvv;
                float wr = 1.f - wl;
                const float* xx = dd + sdi * 16;
                float mx = xx[0];
#pragma unroll
                for (int j = 1; j < 16; j++) mx = fmaxf(mx, xx[j]);
                float se = 0.f;
#pragma unroll
                for (int j = 0; j < 16; j++) se += __expf(xx[j] - mx);
                float lse = mx + __logf(se);
                dfl += (lse - xx[tl]) * wl + (lse - xx[tl + 1]) * wr;
            }
            ldfl = dfl * 0.25f * nv;
        }
    }
    __shared__ float r0[256], r1[256], r2[256], r3[256];
    int tid = threadIdx.x;
    r0[tid] = ts; r1[tid] = cs; r2[tid] = liou; r3[tid] = ldfl;
    __syncthreads();
    for (int s = 128; s > 0; s >>= 1) {
        if (tid < s) {
            r0[tid] += r0[tid + s]; r1[tid] += r1[tid + s];
            r2[tid] += r2[tid + s]; r3[tid] += r3[tid + s];
        }
        __syncthreads();
    }
    if (tid == 0) {
        atomicAdd(&acc[0], r0[0]); atomicAdd(&acc[1], r1[0]);
        atomicAdd(&acc[2], r2[0]); atomicAdd(&acc[3], r3[0]);
    }
}

// ------------------------------------------- K5: finalize
__global__ void k_final(const float* __restrict__ acc, float* __restrict__ out) {
    if (threadIdx.x == 0) {
        float tss = fmaxf(acc[0], 1.f);
        out[0] = acc[2] / tss * 7.5f;   // loss_iou * HYP_BOX
        out[1] = acc[1] / tss * 0.5f;   // loss_cls * HYP_CLS
        out[2] = acc[3] / tss * 1.5f;   // loss_dfl * HYP_DFL
    }
}

extern "C" void kernel_launch(void* const* d_in, const int* in_sizes, int n_in,
                              void* d_out, int out_size, void* d_ws, size_t ws_size,
                              hipStream_t stream) {
    const float* scores = (const float*)d_in[0];   // [B,A,NC]
    const float* distri = (const float*)d_in[1];   // [B,A,64]
    const float* gtb    = (const float*)d_in[4];   // [B,M,4] (pixels)
    const float* mgt    = (const float*)d_in[5];   // [B,M]
    const int*   glab   = (const int*)d_in[6];     // [B,M]
    float* out = (float*)d_out;

    // workspace layout (~11 MiB); ovmax first for 8-byte alignment
    unsigned long long* ovmax = (unsigned long long*)d_ws;          // B*A u64
    float* pb    = (float*)(ovmax + (size_t)B_ * A_);               // B*A*4
    float* alv   = pb + (size_t)B_ * A_ * 4;                        // B*A
    int*   tgti  = (int*)(alv + (size_t)B_ * A_);                   // B*A
    float* acc   = (float*)(tgti + (size_t)B_ * A_);                // 4    --+ zeroed
    int*   pa_g  = (int*)(acc + 4);                                 // B*M    |
    int*   po_g  = pa_g + B_ * M_;                                  // B*M  --+
    unsigned int* abits = (unsigned int*)(po_g + B_ * M_);          // B*A*2 (init in k_init_dfl)

    size_t zero_bytes = (4 + 2 * B_ * M_) * sizeof(int);
    hipMemsetAsync(acc, 0, zero_bytes, stream);

    k_init_dfl<<<2048, 256, 0, stream>>>((const float4*)distri, pb,
                                         (unsigned long long*)abits, ovmax);
    k_aligntopk<<<B_ * M_, 256, 0, stream>>>(scores, pb, gtb, mgt, glab, abits, ovmax);
    k_R<<<1050, 256, 0, stream>>>(abits, ovmax, pb, scores, gtb, glab, tgti, alv, pa_g, po_g);
    k_S<<<2100, 256, 0, stream>>>(tgti, alv, pa_g, po_g, scores, pb, gtb, glab, distri, acc);
    k_final<<<1, 64, 0, stream>>>(acc, out);
    (void)in_sizes; (void)n_in; (void)out_size; (void)ws_size;
}

// Round 7
// 230.036 us; speedup vs baseline: 1.3495x; 1.3495x over previous
//
#include <hip/hip_runtime.h>
#include <math.h>

#define B_    32
#define A_    8400
#define M_    40
#define NC_   80
#define TOPK_ 10
#define EPS_  1e-9f

#define NTHR  524288   // k_stream grid is EXACTLY 2048 x 256 = NTHR threads

// ---------------------------------------------------------------- CIoU
__device__ __forceinline__ float ciou_f(float b1x1, float b1y1, float b1x2, float b1y2,
                                        float b2x1, float b2y1, float b2x2, float b2y2) {
    const float eps = 1e-7f;
    float w1 = b1x2 - b1x1, h1 = b1y2 - b1y1 + eps;
    float w2 = b2x2 - b2x1, h2 = b2y2 - b2y1 + eps;
    float iw = fminf(b1x2, b2x2) - fmaxf(b1x1, b2x1);
    float ih = fminf(b1y2, b2y2) - fmaxf(b1y1, b2y1);
    float inter = fmaxf(iw, 0.f) * fmaxf(ih, 0.f);
    float uni = w1 * h1 + w2 * h2 - inter + eps;
    float iou = inter / uni;
    float cw = fmaxf(b1x2, b2x2) - fminf(b1x1, b2x1);
    float ch = fmaxf(b1y2, b2y2) - fminf(b1y1, b2y1);
    float c2 = cw * cw + ch * ch + eps;
    float dx = b2x1 + b2x2 - b1x1 - b1x2;
    float dy = b2y1 + b2y2 - b1y1 - b1y2;
    float rho2 = (dx * dx + dy * dy) * 0.25f;
    float da = atanf(w2 / h2) - atanf(w1 / h1);
    float v = 0.4052847345693511f * da * da;       // 4/pi^2
    float alpha = v / (v - iou + 1.f + eps);
    return iou - (rho2 / c2 + v * alpha);
}

// closed-form anchor: grid-unit center (ax,ay) and stride s for anchor index a
__device__ __forceinline__ void anchor_of(int a, float& ax, float& ay, float& s) {
    if (a < 6400)      { s = 8.f;  int r = a;        ax = (float)(r % 80) + 0.5f; ay = (float)(r / 80) + 0.5f; }
    else if (a < 8000) { s = 16.f; int r = a - 6400; ax = (float)(r % 40) + 0.5f; ay = (float)(r / 40) + 0.5f; }
    else               { s = 32.f; int r = a - 8000; ax = (float)(r % 20) + 0.5f; ay = (float)(r / 20) + 0.5f; }
}

// masked overlap at (b, gt-box g, anchor a); 0 if anchor center outside box
__device__ __forceinline__ float ov_at2(const float* __restrict__ pb,
                                        float g0, float g1, float g2, float g3,
                                        int b, int a) {
    float ax, ay, s; anchor_of(a, ax, ay, s);
    float axp = ax * s, ayp = ay * s;
    if (!((axp - g0) > EPS_ && (ayp - g1) > EPS_ && (g2 - axp) > EPS_ && (g3 - ayp) > EPS_))
        return 0.f;
    const float4 p = *(const float4*)(pb + ((size_t)b * A_ + a) * 4);
    float c = ciou_f(g0, g1, g2, g3, p.x * s, p.y * s, p.z * s, p.w * s);
    return fmaxf(c, 0.f);
}

__device__ __forceinline__ unsigned long long shflxor_u64(unsigned long long v, int m) {
    int lo = __shfl_xor((int)(unsigned)(v & 0xffffffffull), m, 64);
    int hi = __shfl_xor((int)(unsigned)(v >> 32), m, 64);
    return ((unsigned long long)(unsigned)hi << 32) | (unsigned)lo;
}

// ---- DPP cross-lane helpers (VALU pipe, no LDS) --------------------------
__device__ __forceinline__ float qsum_dpp(float v) {
    int y = __builtin_amdgcn_update_dpp(0, __float_as_int(v), 0xB1, 0xF, 0xF, true);   // quad_perm xor1
    float r = v + __int_as_float(y);
    int z = __builtin_amdgcn_update_dpp(0, __float_as_int(r), 0x4E, 0xF, 0xF, true);   // quad_perm xor2
    return r + __int_as_float(z);
}

template <int CTRL>
__device__ __forceinline__ unsigned long long dpp64(unsigned long long v) {
    unsigned lo = (unsigned)__builtin_amdgcn_update_dpp(0, (int)(unsigned)v, CTRL, 0xF, 0xF, true);
    unsigned hi = (unsigned)__builtin_amdgcn_update_dpp(0, (int)(unsigned)(v >> 32), CTRL, 0xF, 0xF, true);
    return ((unsigned long long)hi << 32) | lo;
}

__device__ __forceinline__ unsigned long long max64(unsigned long long a, unsigned long long b) {
    return a > b ? a : b;
}

__device__ __forceinline__ unsigned long long swz16_64(unsigned long long v) {
    unsigned lo = (unsigned)__builtin_amdgcn_ds_swizzle((int)(unsigned)v, 0x401F);        // xor16 (BitMode)
    unsigned hi = (unsigned)__builtin_amdgcn_ds_swizzle((int)(unsigned)(v >> 32), 0x401F);
    return ((unsigned long long)hi << 32) | lo;
}

// all-lanes max of u64 key across the wave (valid under max-reduce block-uniformity)
__device__ __forceinline__ unsigned long long wave_max_u64(unsigned long long w) {
    w = max64(w, dpp64<0xB1>(w));    // xor1
    w = max64(w, dpp64<0x4E>(w));    // xor2
    w = max64(w, dpp64<0x141>(w));   // row_half_mirror (covers 8-group)
    w = max64(w, dpp64<0x140>(w));   // row_mirror      (covers 16-group)
    w = max64(w, swz16_64(w));       // xor16           (covers 32-group)
    w = max64(w, shflxor_u64(w, 32));// xor32           (covers 64)
    return w;
}

// quad-cooperative 16-bin softmax-expectation; f is the float4 index
__device__ __forceinline__ void dfl_quad(float4 v, int f, float* __restrict__ pb) {
    int q = f & 3;
    float e0 = __expf(v.x), e1 = __expf(v.y), e2 = __expf(v.z), e3 = __expf(v.w);
    float se = e0 + e1 + e2 + e3;
    float sd = e1 + 2.f * e2 + 3.f * e3 + (float)(4 * q) * se;
    se = qsum_dpp(se);
    sd = qsum_dpp(sd);
    float dist = sd / se;
    // lane i reads lane i+N ==> row_shl:N (0x100+N)
    int di = __float_as_int(dist);
    float d1 = __int_as_float(__builtin_amdgcn_update_dpp(0, di, 0x104, 0xF, 0xF, true)); // row_shl:4
    float d2 = __int_as_float(__builtin_amdgcn_update_dpp(0, di, 0x108, 0xF, 0xF, true)); // row_shl:8
    float d3 = __int_as_float(__builtin_amdgcn_update_dpp(0, di, 0x10C, 0xF, 0xF, true)); // row_shl:12
    if ((f & 15) == 0) {
        int aidx = f >> 4;
        int a = aidx % A_;
        float ax, ay, s; anchor_of(a, ax, ay, s);
        ((float4*)pb)[aidx] = make_float4(ax - dist, ay - d1, ax + d2, ay + d3);
    }
}

__device__ __forceinline__ float bce4(float4 x) {
    return fmaxf(x.x, 0.f) + __logf(1.f + __expf(-fabsf(x.x)))
         + fmaxf(x.y, 0.f) + __logf(1.f + __expf(-fabsf(x.y)))
         + fmaxf(x.z, 0.f) + __logf(1.f + __expf(-fabsf(x.z)))
         + fmaxf(x.w, 0.f) + __logf(1.f + __expf(-fabsf(x.w)));
}

// ------------------------------------------- K1: init + DFL-decode + streaming BCE
// (byte-identical to the r2 config measured at 69-71 us, passed twice)
// Grid MUST be 2048 x 256 (= NTHR threads).
__global__ void k_stream(const float4* __restrict__ d4,
                         const float4* __restrict__ s4,
                         float* __restrict__ pb,
                         unsigned long long* __restrict__ abits64,
                         unsigned long long* __restrict__ ovmax,
                         float* __restrict__ acc) {
    const int tid0 = blockIdx.x * blockDim.x + threadIdx.x;
    if (tid0 < B_ * A_) {
        abits64[tid0] = 0ull;
        ovmax[tid0] = 0x00000000FFFFFFFFull;       // (ov=0.0, m=0)
    }
    {
        const int NF4 = B_ * A_ * 16;
        float4 v0 = d4[tid0];
        float4 v1 = d4[tid0 + NTHR];
        float4 v2 = d4[tid0 + 2 * NTHR];
        float4 v3 = d4[tid0 + 3 * NTHR];
        float4 v4 = d4[tid0 + 4 * NTHR];
        float4 v5 = d4[tid0 + 5 * NTHR];
        float4 v6 = d4[tid0 + 6 * NTHR];
        float4 v7 = d4[tid0 + 7 * NTHR];
        dfl_quad(v0, tid0, pb);
        dfl_quad(v1, tid0 + NTHR, pb);
        dfl_quad(v2, tid0 + 2 * NTHR, pb);
        dfl_quad(v3, tid0 + 3 * NTHR, pb);
        dfl_quad(v4, tid0 + 4 * NTHR, pb);
        dfl_quad(v5, tid0 + 5 * NTHR, pb);
        dfl_quad(v6, tid0 + 6 * NTHR, pb);
        dfl_quad(v7, tid0 + 7 * NTHR, pb);
        int f8 = tid0 + 8 * NTHR;
        if (f8 < NF4) dfl_quad(d4[f8], f8, pb);    // wave-uniform tail
    }
    float sum = 0.f;
    {
        const int N4 = B_ * A_ * (NC_ / 4);
        float4 x0 = s4[tid0];
        float4 x1 = s4[tid0 + NTHR];
        float4 x2 = s4[tid0 + 2 * NTHR];
        float4 x3 = s4[tid0 + 3 * NTHR];
        float4 x4 = s4[tid0 + 4 * NTHR];
        float4 x5 = s4[tid0 + 5 * NTHR];
        float4 x6 = s4[tid0 + 6 * NTHR];
        float4 x7 = s4[tid0 + 7 * NTHR];
        sum += bce4(x0); sum += bce4(x1); sum += bce4(x2); sum += bce4(x3);
        sum += bce4(x4); sum += bce4(x5); sum += bce4(x6); sum += bce4(x7);
        float4 x8 = s4[tid0 + 8 * NTHR];
        float4 x9 = s4[tid0 + 9 * NTHR];
        sum += bce4(x8); sum += bce4(x9);
        int f10 = tid0 + 10 * NTHR;
        if (f10 < N4) sum += bce4(s4[f10]);        // wave-uniform tail
    }
    __shared__ float sh[256];
    sh[threadIdx.x] = sum; __syncthreads();
    for (int s = 128; s > 0; s >>= 1) {
        if (threadIdx.x < s) sh[threadIdx.x] += sh[threadIdx.x + s];
        __syncthreads();
    }
    if (threadIdx.x == 0) atomicAdd(&acc[1], sh[0]);
}

// ------------------------------------------- K2: rect-scan align + top-10 (r4 version, passed 2x)
__global__ __launch_bounds__(256) void k_aligntopk(
    const float* __restrict__ scores, const float* __restrict__ pb,
    const float* __restrict__ gt, const float* __restrict__ mgt,
    const int* __restrict__ glab, unsigned int* __restrict__ abits,
    unsigned long long* __restrict__ ovmax) {
    __shared__ unsigned long long sh[4 * TOPK_];
    int bm = blockIdx.x;
    if (mgt[bm] <= 0.f) return;                 // uniform early-exit, no barrier reached
    int b = bm / M_, m = bm % M_;
    int lab = glab[bm];
    const float g0 = gt[bm * 4 + 0], g1 = gt[bm * 4 + 1];
    const float g2 = gt[bm * 4 + 2], g3 = gt[bm * 4 + 3];
    int tid  = threadIdx.x;
    int lane = tid & 63;
    int wv   = tid >> 6;

    const int   Wl[3]  = { 80, 40, 20 };
    const int   Bs[3]  = { 0, 6400, 8000 };
    const float Sl[3]  = { 8.f, 16.f, 32.f };
    int jlo[3], ilo[3], rw[3], cnt[3];
#pragma unroll
    for (int l = 0; l < 3; l++) {
        float s = Sl[l]; int W = Wl[l];
        int jl = max(0, (int)floorf(g0 / s - 0.5f) - 1);
        int jh = min(W - 1, (int)ceilf(g2 / s - 0.5f) + 1);
        int il = max(0, (int)floorf(g1 / s - 0.5f) - 1);
        int ih = min(W - 1, (int)ceilf(g3 / s - 0.5f) + 1);
        int w = jh - jl + 1, h = ih - il + 1;
        jlo[l] = jl; ilo[l] = il; rw[l] = max(w, 0);
        cnt[l] = (w > 0 && h > 0) ? w * h : 0;
    }
    int c01 = cnt[0] + cnt[1];
    int tot = c01 + cnt[2];

    unsigned long long t[TOPK_];
#pragma unroll
    for (int k = 0; k < TOPK_; k++) t[k] = 0ull;

    for (int c = tid; c < tot; c += 256) {
        int l = (c < cnt[0]) ? 0 : ((c < c01) ? 1 : 2);
        int r = c - ((l == 0) ? 0 : ((l == 1) ? cnt[0] : c01));
        int w = rw[l];
        int di = r / w, dj = r - di * w;
        int i = ilo[l] + di, j = jlo[l] + dj;
        float s = Sl[l];
        float ax = ((float)j + 0.5f) * s;
        float ay = ((float)i + 0.5f) * s;
        if (!((ax - g0) > EPS_ && (ay - g1) > EPS_ && (g2 - ax) > EPS_ && (g3 - ay) > EPS_))
            continue;
        int a = Bs[l] + i * Wl[l] + j;
        // issue BOTH gathers before CIoU so the two latencies overlap
        const float4 p = *(const float4*)(pb + ((size_t)b * A_ + a) * 4);
        float sc = scores[((size_t)b * A_ + a) * NC_ + lab];
        float ci = ciou_f(g0, g1, g2, g3, p.x * s, p.y * s, p.z * s, p.w * s);
        float ov = fmaxf(ci, 0.f);
        float al = 0.f;
        if (ov > 0.f) {
            unsigned long long opk = ((unsigned long long)__float_as_uint(ov) << 32)
                                     | (unsigned)(~(unsigned)m);
            atomicMax(&ovmax[(size_t)b * A_ + a], opk);
            float bs = 1.f / (1.f + __expf(-sc));
            float o2 = ov * ov;
            al = sqrtf(bs) * o2 * o2 * o2;     // bs^0.5 * ov^6
        }
        unsigned long long pkd = ((unsigned long long)__float_as_uint(al) << 32)
                                 | (unsigned)(~(unsigned)a);
        if (pkd > t[TOPK_ - 1]) {
            unsigned long long cv = pkd;
#pragma unroll
            for (int k = 0; k < TOPK_; k++) {
                bool g = cv > t[k];
                unsigned long long o = t[k];
                t[k] = g ? cv : o;
                cv   = g ? o : cv;
            }
        }
    }

    // per-wave top-10 extraction: after this, lanes 0..9 hold the wave's top-10
    unsigned long long mysel = 0ull;
#pragma unroll
    for (int k = 0; k < TOPK_; k++) {
        unsigned long long w = wave_max_u64(t[0]);
        if (lane == k) mysel = w;
        if (w != 0ull && t[0] == w) {
#pragma unroll
            for (int q = 0; q < TOPK_ - 1; q++) t[q] = t[q + 1];
            t[TOPK_ - 1] = 0ull;
        }
    }
    if (lane < TOPK_) sh[wv * TOPK_ + lane] = mysel;
    __syncthreads();
    if (wv != 0) return;                        // no barriers after this point

    // wave 0: merge 40 candidates (keys unique -> exact global top-10)
    unsigned long long val = (lane < 4 * TOPK_) ? sh[lane] : 0ull;
    unsigned long long fin = 0ull;
#pragma unroll
    for (int k = 0; k < TOPK_; k++) {
        unsigned long long w = wave_max_u64(val);
        if (lane == k) fin = w;
        if (w != 0ull && val == w) val = 0ull;
    }

    float sval = __uint_as_float((unsigned)(fin >> 32));
    int   sidx = (int)(~(unsigned)fin);
    unsigned int bit = 1u << (m & 31);
    int word = (m >= 32) ? 1 : 0;
    bool keep = (lane < TOPK_) && (sval > EPS_);
    if (keep) atomicOr(&abits[2 * ((size_t)b * A_ + sidx) + word], bit);
    unsigned long long kb = __ballot(keep);
    if (lane == 0 && __popcll(kb) < TOPK_) {
        float ax = 4.f, ay = 4.f;               // anchor 0 center in pixels
        if ((ax - g0) > EPS_ && (ay - g1) > EPS_ && (g2 - ax) > EPS_ && (g3 - ay) > EPS_)
            atomicOr(&abits[2 * ((size_t)b * A_) + word], bit);
    }
}

// ------------------------------------------- K3: resolve + per-gt maxima + per-gt WEIGHTED SUMS
// The nv-weighted losses are linear in al per anchor times per-gt f = po/(pa+eps):
//   sum_anchors nv*x = sum_g f_g * (sum_{i in g} al_i * x_i)
// so we accumulate S_g = {sum al, sum al*sc, sum al*(1-iou), sum al*dfl/4} here
// and k_final applies f_g. This deletes the old k_S (96 us) entirely.
__global__ __launch_bounds__(256) void k_R(
    const unsigned int* __restrict__ abits,
    const unsigned long long* __restrict__ ovmax,
    const float* __restrict__ pb,
    const float* __restrict__ scores, const float* __restrict__ gt,
    const int* __restrict__ glab, const float* __restrict__ distri,
    int* __restrict__ pa_g, int* __restrict__ po_g,
    float* __restrict__ gsum) {
    int idx = blockIdx.x * blockDim.x + threadIdx.x;
    if (idx >= B_ * A_) return;
    unsigned int lo = abits[2 * idx], hi = abits[2 * idx + 1];
    int fg = __popc(lo) + __popc(hi);
    if (fg == 0) return;
    int b = idx / A_, a = idx % A_;
    int tgt; float ov;
    if (fg > 1) {
        unsigned long long pk = ovmax[idx];    // precomputed argmax over masked overlaps
        tgt = (int)(~(unsigned)(pk & 0xffffffffull));
        ov  = __uint_as_float((unsigned)(pk >> 32));
    } else {
        tgt = lo ? (__ffs(lo) - 1) : (32 + __ffs(hi) - 1);
        int bmi0 = b * M_ + tgt;
        ov = ov_at2(pb, gt[bmi0 * 4], gt[bmi0 * 4 + 1], gt[bmi0 * 4 + 2], gt[bmi0 * 4 + 3], b, a);
    }
    int bmi = b * M_ + tgt;
    float al = 0.f;
    if (ov > 0.f) {
        int lab = glab[bmi];
        float sc = scores[(size_t)idx * NC_ + lab];
        float bs = 1.f / (1.f + __expf(-sc));
        float o2 = ov * ov;
        al = sqrtf(bs) * o2 * o2 * o2;
    }
    atomicMax(&pa_g[bmi], __float_as_int(al));
    atomicMax(&po_g[bmi], __float_as_int(ov));
    if (al > 0.f) {
        int lab2 = max(glab[bmi], 0);
        float sc2 = scores[(size_t)idx * NC_ + lab2];
        // CIoU in grid units
        float ax, ay, s; anchor_of(a, ax, ay, s);
        const float* g = gt + (size_t)bmi * 4;
        float t0 = g[0] / s, t1 = g[1] / s, t2 = g[2] / s, t3 = g[3] / s;
        const float4 p = *(const float4*)(pb + (size_t)idx * 4);
        float iou = ciou_f(p.x, p.y, p.z, p.w, t0, t1, t2, t3);
        // DFL
        float tg4[4] = { ax - t0, ay - t1, t2 - ax, t3 - ay };
        const float* dd = distri + (size_t)idx * 64;
        float dfl = 0.f;
#pragma unroll
        for (int sd = 0; sd < 4; sd++) {
            float tvv = fminf(fmaxf(tg4[sd], 0.f), 14.99f);
            int tl = (int)tvv;
            float wl = (float)(tl + 1) - tvv;
            float wr = 1.f - wl;
            const float* xx = dd + sd * 16;
            float mx = xx[0];
#pragma unroll
            for (int j = 1; j < 16; j++) mx = fmaxf(mx, xx[j]);
            float se = 0.f;
#pragma unroll
            for (int j = 0; j < 16; j++) se += __expf(xx[j] - mx);
            float lse = mx + __logf(se);
            dfl += (lse - xx[tl]) * wl + (lse - xx[tl + 1]) * wr;
        }
        atomicAdd(&gsum[bmi * 4 + 0], al);
        atomicAdd(&gsum[bmi * 4 + 1], al * sc2);
        atomicAdd(&gsum[bmi * 4 + 2], al * (1.f - iou));
        atomicAdd(&gsum[bmi * 4 + 3], al * dfl * 0.25f);
    }
}

// ------------------------------------------- K4: finalize — apply per-gt factor and reduce
__global__ __launch_bounds__(256) void k_final(
    const float* __restrict__ acc, const int* __restrict__ pa_g,
    const int* __restrict__ po_g, const float* __restrict__ gsum,
    float* __restrict__ out) {
    int tid = threadIdx.x;
    float ts = 0.f, cls = 0.f, li = 0.f, ld = 0.f;
    for (int g = tid; g < B_ * M_; g += 256) {
        float pa = __int_as_float(pa_g[g]);
        float po = __int_as_float(po_g[g]);
        float f = po / (pa + EPS_);
        ts  += f * gsum[g * 4 + 0];
        cls += f * gsum[g * 4 + 1];
        li  += f * gsum[g * 4 + 2];
        ld  += f * gsum[g * 4 + 3];
    }
    __shared__ float r0[256], r1[256], r2[256], r3[256];
    r0[tid] = ts; r1[tid] = cls; r2[tid] = li; r3[tid] = ld;
    __syncthreads();
    for (int s = 128; s > 0; s >>= 1) {
        if (tid < s) {
            r0[tid] += r0[tid + s]; r1[tid] += r1[tid + s];
            r2[tid] += r2[tid + s]; r3[tid] += r3[tid + s];
        }
        __syncthreads();
    }
    if (tid == 0) {
        float tss = fmaxf(r0[0], 1.f);
        out[0] = r2[0] / tss * 7.5f;                 // loss_iou * HYP_BOX
        out[1] = (acc[1] - r1[0]) / tss * 0.5f;      // loss_cls * HYP_CLS
        out[2] = r3[0] / tss * 1.5f;                 // loss_dfl * HYP_DFL
    }
}

extern "C" void kernel_launch(void* const* d_in, const int* in_sizes, int n_in,
                              void* d_out, int out_size, void* d_ws, size_t ws_size,
                              hipStream_t stream) {
    const float* scores = (const float*)d_in[0];   // [B,A,NC]
    const float* distri = (const float*)d_in[1];   // [B,A,64]
    const float* gtb    = (const float*)d_in[4];   // [B,M,4] (pixels)
    const float* mgt    = (const float*)d_in[5];   // [B,M]
    const int*   glab   = (const int*)d_in[6];     // [B,M]
    float* out = (float*)d_out;

    // workspace layout (~8.6 MiB); ovmax first for 8-byte alignment;
    // acc..gsum contiguous so one memset covers them; abits offset is 8B-aligned.
    unsigned long long* ovmax = (unsigned long long*)d_ws;          // B*A u64
    float* pb    = (float*)(ovmax + (size_t)B_ * A_);               // B*A*4
    float* acc   = pb + (size_t)B_ * A_ * 4;                        // 4    --+ zeroed
    int*   pa_g  = (int*)(acc + 4);                                 // B*M    |
    int*   po_g  = pa_g + B_ * M_;                                  // B*M    |
    float* gsum  = (float*)(po_g + B_ * M_);                        // B*M*4--+
    unsigned int* abits = (unsigned int*)(gsum + (size_t)B_ * M_ * 4); // B*A*2 (init in k_stream)

    size_t zero_bytes = (4 + 2 * B_ * M_ + 4 * B_ * M_) * sizeof(float);
    hipMemsetAsync(acc, 0, zero_bytes, stream);

    k_stream<<<2048, 256, 0, stream>>>((const float4*)distri, (const float4*)scores, pb,
                                       (unsigned long long*)abits, ovmax, acc);
    k_aligntopk<<<B_ * M_, 256, 0, stream>>>(scores, pb, gtb, mgt, glab, abits, ovmax);
    k_R<<<1050, 256, 0, stream>>>(abits, ovmax, pb, scores, gtb, glab, distri,
                                  pa_g, po_g, gsum);
    k_final<<<1, 256, 0, stream>>>(acc, pa_g, po_g, gsum, out);
    (void)in_sizes; (void)n_in; (void)out_size; (void)ws_size;
}